// Round 3
// baseline (747.250 us; speedup 1.0000x reference)
//
#include <hip/hip_runtime.h>

#define PD 88      // sequences == W dim
#define TD 128     // time == T dim
#define I0 133     // layer0 input size
#define HID 24     // LSTM hidden
#define GD 96      // gates = 4*HID
#define CD 48      // channels = 2*HID
#define NH 4       // heads
#define HDIM 12    // head dim
#define KW 13      // neighborhood

__device__ __forceinline__ int imin(int a,int b){return a<b?a:b;}
__device__ __forceinline__ int imax(int a,int b){return a>b?a:b;}

// activated gate: sigmoid (sa=1,ss=1,sb=0) or tanh (sa=2,ss=2,sb=-1)
__device__ __forceinline__ float actg(float sa, float ss, float sb, float x) {
  return sa * __builtin_amdgcn_rcpf(1.f + __expf(-ss * x)) + sb;
}

// ============ xg layer0 ============
// XG[dir][p][t][g]; grid (352, 2), block 128 (96 compute cols), R=32 rows.
// W in LDS stride 133 (odd -> conflict-free b32); A in LDS, broadcast b128.
__global__ __launch_bounds__(128) void xg0_kernel(
    const float* __restrict__ x,
    const float* __restrict__ wf, const float* __restrict__ wb,
    const float* __restrict__ bif, const float* __restrict__ bhf,
    const float* __restrict__ bib, const float* __restrict__ bhb,
    float* __restrict__ xg) {
  __shared__ float wl[GD*I0];        // 51.1 KB, row-major [96][133]
  __shared__ float al[32*136];       // 17.4 KB, stride 136 (16B aligned)
  const int dir = blockIdx.y;
  const float* W = dir ? wb : wf;
  for (int idx = threadIdx.x; idx < GD*I0; idx += 128)
    wl[idx] = W[idx];
  const int r0 = blockIdx.x * 32;
  const int p = r0 >> 7, t0 = r0 & 127;
  for (int idx = threadIdx.x; idx < 32*I0; idx += 128) {
    int r = idx / I0, i = idx - r*I0;
    al[r*136 + i] = x[((size_t)(t0+r)*PD + p)*I0 + i];
  }
  __syncthreads();
  const int c = threadIdx.x;
  if (c >= GD) return;
  const float bias = (dir ? (bib[c]+bhb[c]) : (bif[c]+bhf[c]));
  float acc[32];
#pragma unroll
  for (int r=0;r<32;r++) acc[r]=bias;
  const float* wrow = wl + c*I0;
  for (int i0=0; i0<132; i0+=4) {
    float w0=wrow[i0], w1=wrow[i0+1], w2=wrow[i0+2], w3=wrow[i0+3];
#pragma unroll
    for (int r=0;r<32;r++) {
      float4 a4 = *reinterpret_cast<const float4*>(&al[r*136 + i0]);  // broadcast
      acc[r] += a4.x*w0 + a4.y*w1 + a4.z*w2 + a4.w*w3;
    }
  }
  {
    float wlast = wrow[132];
#pragma unroll
    for (int r=0;r<32;r++) acc[r] += al[r*136 + 132]*wlast;
  }
  float* op = xg + ((size_t)dir*PD*TD + r0)*GD + c;
#pragma unroll
  for (int r=0;r<32;r++) op[(size_t)r*GD] = acc[r];
}

// ============ xg layer1 ============
// input H0 rows (p*128+t) x 48; 192 cols (fwd 0..95, bwd 96..191).
__global__ __launch_bounds__(192) void xg1_kernel(
    const float* __restrict__ h0,
    const float* __restrict__ wf, const float* __restrict__ wb,
    const float* __restrict__ bif, const float* __restrict__ bhf,
    const float* __restrict__ bib, const float* __restrict__ bhb,
    float* __restrict__ xg) {
  __shared__ float wl[192*52];       // 39.9 KB
  __shared__ float al[32*CD];        // 6 KB
  for (int idx = threadIdx.x; idx < 192*CD; idx += 192) {
    int cc = idx / CD, i = idx - cc*CD;
    wl[cc*52 + i] = (cc < GD) ? wf[cc*CD + i] : wb[(cc-GD)*CD + i];
  }
  const int r0 = blockIdx.x * 32;
  for (int idx = threadIdx.x; idx < 32*CD/4; idx += 192)
    reinterpret_cast<float4*>(al)[idx] =
        reinterpret_cast<const float4*>(h0 + (size_t)r0*CD)[idx];
  __syncthreads();
  const int c = threadIdx.x;
  const int dir = c >= GD;
  const int g = c - dir*GD;
  const float bias = dir ? (bib[g]+bhb[g]) : (bif[g]+bhf[g]);
  float4 wr[12];
#pragma unroll
  for (int i=0;i<12;i++) wr[i] = *reinterpret_cast<const float4*>(&wl[c*52 + 4*i]);
  float acc[32];
#pragma unroll
  for (int r=0;r<32;r++) acc[r]=bias;
#pragma unroll
  for (int i=0;i<12;i++) {
    float4 w4 = wr[i];
#pragma unroll
    for (int r=0;r<32;r++) {
      float4 a4 = *reinterpret_cast<const float4*>(&al[r*CD + 4*i]);  // broadcast
      acc[r] += a4.x*w4.x + a4.y*w4.y + a4.z*w4.z + a4.w*w4.w;
    }
  }
  float* op = xg + (size_t)dir*PD*TD*GD + (size_t)r0*GD + g;
#pragma unroll
  for (int r=0;r<32;r++) op[(size_t)r*GD] = acc[r];
}

// ============ bidirectional LSTM: one wave per (seq,dir) ============
// All-register recurrence: w_hh rows in VGPRs, h in SGPRs (readlane),
// gate exchange via bpermute. No LDS, no barriers.
__global__ __launch_bounds__(64) void lstm_kernel(
    const float* __restrict__ xg,
    const float* __restrict__ whf, const float* __restrict__ whb,
    float* __restrict__ out, const int mode) {
  const int p = blockIdx.x >> 1;
  const int dir = blockIdx.x & 1;
  const int l = threadIdx.x;
  const float* wh = dir ? whb : whf;
  const int gA = l;                  // gate l (0..63)
  const int gB = 64 + (l & 31);      // gate 64..95
  float wA[HID], wB[HID];
#pragma unroll
  for (int j=0;j<HID;j+=4) {
    float4 a4 = *reinterpret_cast<const float4*>(wh + gA*HID + j);
    wA[j]=a4.x; wA[j+1]=a4.y; wA[j+2]=a4.z; wA[j+3]=a4.w;
    float4 b4 = *reinterpret_cast<const float4*>(wh + gB*HID + j);
    wB[j]=b4.x; wB[j+1]=b4.y; wB[j+2]=b4.z; wB[j+3]=b4.w;
  }
  const bool tA = (gA >= 48);              // gate g-range 48..71
  const bool tB = ((l & 31) < 8);
  const float saA = tA?2.f:1.f, ssA = tA?2.f:1.f, sbA = tA?-1.f:0.f;
  const float saB = tB?2.f:1.f, ssB = tB?2.f:1.f, sbB = tB?-1.f:0.f;
  float h[HID];
#pragma unroll
  for (int j=0;j<HID;j++) h[j]=0.f;
  float c = 0.f;
  const float* xp = xg + ((size_t)dir*PD + p)*TD*GD;
  int t = dir ? TD-1 : 0;
  const int dt = dir ? -1 : 1;
  float xa = xp[t*GD + gA];
  float xb = xp[t*GD + gB];
  for (int s=0; s<TD; ++s) {
    const int tn = t + dt;
    float na = 0.f, nb = 0.f;
    if (s+1 < TD) { na = xp[tn*GD + gA]; nb = xp[tn*GD + gB]; }
    float accA = xa, accB = xb;
#pragma unroll
    for (int j=0;j<HID;j++) { accA += wA[j]*h[j]; accB += wB[j]*h[j]; }
    float vA = actg(saA, ssA, sbA, accA);
    float vB = actg(saB, ssB, sbB, accB);
    // lane l<24 needs: i=gate l (own vA), f=gate 24+l, g=gate 48+l, o=gate 72+l
    float f  = __shfl(vA, (24 + l) & 63);
    float g1 = __shfl(vA, (48 + l) & 63);
    float g2 = __shfl(vB, (l - 16) & 63);
    float o  = __shfl(vB, (8 + l) & 63);
    float gg = (l < 16) ? g1 : g2;
    c = f*c + vA*gg;
    float th = 2.f*__builtin_amdgcn_rcpf(1.f + __expf(-2.f*c)) - 1.f;
    float hn = o * th;
    if (l < HID) {
      if (mode==0) out[((size_t)p*TD + t)*CD + dir*HID + l] = hn;
      else         out[((size_t)t*PD + p)*CD + dir*HID + l] = hn;
    }
#pragma unroll
    for (int j=0;j<HID;j++)
      h[j] = __int_as_float(__builtin_amdgcn_readlane(__float_as_int(hn), j));
    xa = na; xb = nb; t = tn;
  }
}

// ============ qkv projection ============
__global__ __launch_bounds__(192) void qkv_kernel(
    const float* __restrict__ y, const float* __restrict__ wq,
    const float* __restrict__ bq,
    float* __restrict__ Qb, float* __restrict__ Kb, float* __restrict__ Vb) {
  __shared__ float wl[144*52];       // 30 KB
  __shared__ float al[32*CD];        // 6 KB
  for (int idx = threadIdx.x; idx < 144*CD; idx += 192) {
    int cc = idx / CD, i = idx - cc*CD;
    wl[cc*52 + i] = wq[idx];
  }
  const int r0 = blockIdx.x * 32;
  for (int idx = threadIdx.x; idx < 32*CD/4; idx += 192)
    reinterpret_cast<float4*>(al)[idx] =
        reinterpret_cast<const float4*>(y + (size_t)r0*CD)[idx];
  __syncthreads();
  const int c = threadIdx.x;
  if (c >= 144) return;
  float4 wr[12];
#pragma unroll
  for (int i=0;i<12;i++) wr[i] = *reinterpret_cast<const float4*>(&wl[c*52 + 4*i]);
  const float bias = bq[c];
  float acc[32];
#pragma unroll
  for (int r=0;r<32;r++) acc[r]=bias;
#pragma unroll
  for (int i=0;i<12;i++) {
    float4 w4 = wr[i];
#pragma unroll
    for (int r=0;r<32;r++) {
      float4 a4 = *reinterpret_cast<const float4*>(&al[r*CD + 4*i]);
      acc[r] += a4.x*w4.x + a4.y*w4.y + a4.z*w4.z + a4.w*w4.w;
    }
  }
  float* dst; int col; float sc = 1.f;
  if (c < CD)        { dst = Qb; col = c;      sc = 0.28867513459481287f; }
  else if (c < 2*CD) { dst = Kb; col = c-CD; }
  else               { dst = Vb; col = c-2*CD; }
#pragma unroll
  for (int r=0;r<32;r++) dst[(size_t)(r0+r)*CD + col] = acc[r]*sc;
}

// ============ NATTEN 2D (unchanged) ============
__global__ __launch_bounds__(256) void natten_kernel(
    const float* __restrict__ Qb, const float* __restrict__ Kb,
    const float* __restrict__ Vb, const float* __restrict__ rpb,
    float* __restrict__ out) {
  __shared__ float kl[NH*400*HDIM];
  __shared__ float vl[NH*400*HDIM];
  const int tb = blockIdx.x & 15;
  const int wb = blockIdx.x >> 4;
  const int t0 = tb*8, w0 = wb*8;
  const int ht0 = imin(imax(t0-6,0), TD-KW);
  const int hw0 = imin(imax(w0-6,0), PD-KW);
  for (int idx = threadIdx.x; idx < 400*HDIM; idx += 256) {
    int pos = idx / HDIM;
    int c4  = idx - pos*HDIM;
    int lw = pos / 20, lt = pos - lw*20;
    int gt = imin(ht0+lt, TD-1), gw = imin(hw0+lw, PD-1);
    int h = c4 / 3, j = c4 - h*3;
    size_t ga = ((size_t)gt*PD + gw)*CD + c4*4;
    *reinterpret_cast<float4*>(&kl[((size_t)h*400+pos)*HDIM + j*4]) =
        *reinterpret_cast<const float4*>(Kb + ga);
    *reinterpret_cast<float4*>(&vl[((size_t)h*400+pos)*HDIM + j*4]) =
        *reinterpret_cast<const float4*>(Vb + ga);
  }
  __syncthreads();
  const int head = threadIdx.x >> 6;
  const int pix  = threadIdx.x & 63;
  const int pt = pix >> 3, pw = pix & 7;
  const int t = t0+pt, w = w0+pw;
  const int ts = imin(imax(t-6,0), TD-KW);
  const int wsb = imin(imax(w-6,0), PD-KW);
  const int lt0 = ts - ht0, lw0 = wsb - hw0;
  const float* qp = Qb + ((size_t)t*PD + w)*CD + head*HDIM;
  float4 q0 = *reinterpret_cast<const float4*>(qp);
  float4 q1 = *reinterpret_cast<const float4*>(qp+4);
  float4 q2 = *reinterpret_cast<const float4*>(qp+8);
  const float* kb = kl + (size_t)head*4800;
  const float* vb = vl + (size_t)head*4800;
  const float* bb = rpb + head*625 + (ts-t+12)*25 + (wsb-w+12);
  float sum=0.f;
  float o0x=0,o0y=0,o0z=0,o0w=0, o1x=0,o1y=0,o1z=0,o1w=0, o2x=0,o2y=0,o2z=0,o2w=0;
  for (int pp=0; pp<KW; ++pp) {
    const int ltp = lt0+pp;
    const float* br = bb + pp*25;
    for (int qq=0; qq<KW; ++qq) {
      const int pos = (lw0+qq)*20 + ltp;
      const float* kr = kb + pos*HDIM;
      float4 k0=*reinterpret_cast<const float4*>(kr);
      float4 k1=*reinterpret_cast<const float4*>(kr+4);
      float4 k2=*reinterpret_cast<const float4*>(kr+8);
      float lg = br[qq];
      lg += q0.x*k0.x + q0.y*k0.y + q0.z*k0.z + q0.w*k0.w;
      lg += q1.x*k1.x + q1.y*k1.y + q1.z*k1.z + q1.w*k1.w;
      lg += q2.x*k2.x + q2.y*k2.y + q2.z*k2.z + q2.w*k2.w;
      float e = __expf(lg);
      sum += e;
      const float* vr = vb + pos*HDIM;
      float4 v0=*reinterpret_cast<const float4*>(vr);
      float4 v1=*reinterpret_cast<const float4*>(vr+4);
      float4 v2=*reinterpret_cast<const float4*>(vr+8);
      o0x += e*v0.x; o0y += e*v0.y; o0z += e*v0.z; o0w += e*v0.w;
      o1x += e*v1.x; o1y += e*v1.y; o1z += e*v1.z; o1w += e*v1.w;
      o2x += e*v2.x; o2y += e*v2.y; o2z += e*v2.z; o2w += e*v2.w;
    }
  }
  float inv = 1.f/sum;
  float* op = out + ((size_t)t*PD + w)*CD + head*HDIM;
  float4 r0v = {o0x*inv,o0y*inv,o0z*inv,o0w*inv};
  float4 r1v = {o1x*inv,o1y*inv,o1z*inv,o1w*inv};
  float4 r2v = {o2x*inv,o2y*inv,o2z*inv,o2w*inv};
  *reinterpret_cast<float4*>(op)   = r0v;
  *reinterpret_cast<float4*>(op+4) = r1v;
  *reinterpret_cast<float4*>(op+8) = r2v;
}

// ============ output projection ============
// block 256 = 4 row-groups x 64 lanes (48 compute cols), R=32 rows.
__global__ __launch_bounds__(256) void proj_kernel(
    const float* __restrict__ ain, const float* __restrict__ wp,
    const float* __restrict__ bp, float* __restrict__ out) {
  __shared__ float wl[48*52];        // 10 KB
  __shared__ float al[32*CD];        // 6 KB
  for (int idx = threadIdx.x; idx < CD*CD; idx += 256) {
    int cc = idx / CD, i = idx - cc*CD;
    wl[cc*52 + i] = wp[idx];
  }
  const int r0 = blockIdx.x * 32;
  for (int idx = threadIdx.x; idx < 32*CD/4; idx += 256)
    reinterpret_cast<float4*>(al)[idx] =
        reinterpret_cast<const float4*>(ain + (size_t)r0*CD)[idx];
  __syncthreads();
  const int c  = threadIdx.x & 63;
  const int rg = threadIdx.x >> 6;   // 0..3 -> rows rg*8..rg*8+7
  if (c >= CD) return;
  float4 wr[12];
#pragma unroll
  for (int i=0;i<12;i++) wr[i] = *reinterpret_cast<const float4*>(&wl[c*52 + 4*i]);
  const float bias = bp[c];
  float acc[8];
#pragma unroll
  for (int r=0;r<8;r++) acc[r]=bias;
#pragma unroll
  for (int i=0;i<12;i++) {
    float4 w4 = wr[i];
#pragma unroll
    for (int r=0;r<8;r++) {
      float4 a4 = *reinterpret_cast<const float4*>(&al[(rg*8+r)*CD + 4*i]);
      acc[r] += a4.x*w4.x + a4.y*w4.y + a4.z*w4.z + a4.w*w4.w;
    }
  }
#pragma unroll
  for (int r=0;r<8;r++) out[(size_t)(r0+rg*8+r)*CD + c] = acc[r];
}

extern "C" void kernel_launch(void* const* d_in, const int* in_sizes, int n_in,
                              void* d_out, int out_size, void* d_ws, size_t ws_size,
                              hipStream_t stream) {
  (void)in_sizes; (void)n_in; (void)out_size; (void)ws_size;
  const float* x        = (const float*)d_in[0];
  const float* w_ih_l0  = (const float*)d_in[1];
  const float* w_hh_l0  = (const float*)d_in[2];
  const float* b_ih_l0  = (const float*)d_in[3];
  const float* b_hh_l0  = (const float*)d_in[4];
  const float* w_ih_l0r = (const float*)d_in[5];
  const float* w_hh_l0r = (const float*)d_in[6];
  const float* b_ih_l0r = (const float*)d_in[7];
  const float* b_hh_l0r = (const float*)d_in[8];
  const float* w_ih_l1  = (const float*)d_in[9];
  const float* w_hh_l1  = (const float*)d_in[10];
  const float* b_ih_l1  = (const float*)d_in[11];
  const float* b_hh_l1  = (const float*)d_in[12];
  const float* w_ih_l1r = (const float*)d_in[13];
  const float* w_hh_l1r = (const float*)d_in[14];
  const float* b_ih_l1r = (const float*)d_in[15];
  const float* b_hh_l1r = (const float*)d_in[16];
  const float* w_qkv    = (const float*)d_in[17];
  const float* b_qkv    = (const float*)d_in[18];
  const float* rpb      = (const float*)d_in[19];
  const float* w_proj   = (const float*)d_in[20];
  const float* b_proj   = (const float*)d_in[21];
  float* out = (float*)d_out;

  float* ws = (float*)d_ws;
  const size_t NPIX = (size_t)TD*PD;          // 11264
  float* XG = ws;                              // 2*88*128*96 floats
  float* H0 = XG + (size_t)2*PD*TD*GD;
  float* Y  = H0 + NPIX*CD;
  float* Qb = Y  + NPIX*CD;
  float* Kb = Qb + NPIX*CD;
  float* Vb = Kb + NPIX*CD;
  float* AO = Vb + NPIX*CD;

  xg0_kernel<<<dim3(352,2),128,0,stream>>>(x, w_ih_l0, w_ih_l0r, b_ih_l0, b_hh_l0, b_ih_l0r, b_hh_l0r, XG);
  lstm_kernel<<<2*PD,64,0,stream>>>(XG, w_hh_l0, w_hh_l0r, H0, 0);
  xg1_kernel<<<352,192,0,stream>>>(H0, w_ih_l1, w_ih_l1r, b_ih_l1, b_hh_l1, b_ih_l1r, b_hh_l1r, XG);
  lstm_kernel<<<2*PD,64,0,stream>>>(XG, w_hh_l1, w_hh_l1r, Y, 1);

  for (int l=0; l<2; ++l) {
    qkv_kernel<<<352,192,0,stream>>>(Y, w_qkv, b_qkv, Qb, Kb, Vb);
    natten_kernel<<<176,256,0,stream>>>(Qb, Kb, Vb, rpb, AO);
    proj_kernel<<<352,256,0,stream>>>(AO, w_proj, b_proj, (l==1)? out : Y);
  }
}

// Round 4
// 262.963 us; speedup vs baseline: 2.8417x; 2.8417x over previous
//
#include <hip/hip_runtime.h>

#define PD 88      // sequences == W dim
#define TD 128     // time == T dim
#define I0 133     // layer0 input size
#define HID 24     // LSTM hidden
#define GD 96      // gates = 4*HID
#define CD 48      // channels = 2*HID
#define NH 4       // heads
#define HDIM 12    // head dim
#define KW 13      // neighborhood

__device__ __forceinline__ int imin(int a,int b){return a<b?a:b;}
__device__ __forceinline__ int imax(int a,int b){return a>b?a:b;}

__device__ __forceinline__ float actg(float sa, float ss, float sb, float x) {
  return sa * __builtin_amdgcn_rcpf(1.f + __expf(-ss * x)) + sb;
}

// ============ xg layer0 (unchanged from r3 — proven) ============
__global__ __launch_bounds__(128) void xg0_kernel(
    const float* __restrict__ x,
    const float* __restrict__ wf, const float* __restrict__ wb,
    const float* __restrict__ bif, const float* __restrict__ bhf,
    const float* __restrict__ bib, const float* __restrict__ bhb,
    float* __restrict__ xg) {
  __shared__ float wl[GD*I0];        // 51.1 KB, row-major [96][133]
  __shared__ float al[32*136];       // 17.4 KB
  const int dir = blockIdx.y;
  const float* W = dir ? wb : wf;
  for (int idx = threadIdx.x; idx < GD*I0; idx += 128)
    wl[idx] = W[idx];
  const int r0 = blockIdx.x * 32;
  const int p = r0 >> 7, t0 = r0 & 127;
  for (int idx = threadIdx.x; idx < 32*I0; idx += 128) {
    int r = idx / I0, i = idx - r*I0;
    al[r*136 + i] = x[((size_t)(t0+r)*PD + p)*I0 + i];
  }
  __syncthreads();
  const int c = threadIdx.x;
  if (c >= GD) return;
  const float bias = (dir ? (bib[c]+bhb[c]) : (bif[c]+bhf[c]));
  float acc[32];
#pragma unroll
  for (int r=0;r<32;r++) acc[r]=bias;
  const float* wrow = wl + c*I0;
#pragma unroll 1
  for (int i0=0; i0<132; i0+=4) {
    float w0=wrow[i0], w1=wrow[i0+1], w2=wrow[i0+2], w3=wrow[i0+3];
#pragma unroll
    for (int r=0;r<32;r++) {
      float4 a4 = *reinterpret_cast<const float4*>(&al[r*136 + i0]);  // broadcast
      acc[r] += a4.x*w0 + a4.y*w1 + a4.z*w2 + a4.w*w3;
    }
  }
  {
    float wlast = wrow[132];
#pragma unroll
    for (int r=0;r<32;r++) acc[r] += al[r*136 + 132]*wlast;
  }
  float* op = xg + ((size_t)dir*PD*TD + r0)*GD + c;
#pragma unroll
  for (int r=0;r<32;r++) op[(size_t)r*GD] = acc[r];
}

// ============ xg layer1 — xg0-style: weights from LDS scalars, unroll-pinned ============
__global__ __launch_bounds__(192) void xg1_kernel(
    const float* __restrict__ h0,
    const float* __restrict__ wf, const float* __restrict__ wb,
    const float* __restrict__ bif, const float* __restrict__ bhf,
    const float* __restrict__ bib, const float* __restrict__ bhb,
    float* __restrict__ xg) {
  __shared__ float wl[192*53];       // 40.7 KB, stride 53 (odd -> conflict-free)
  __shared__ float al[32*CD];        // 6 KB
  for (int idx = threadIdx.x; idx < 192*CD; idx += 192) {
    int cc = idx / CD, i = idx - cc*CD;
    wl[cc*53 + i] = (cc < GD) ? wf[cc*CD + i] : wb[(cc-GD)*CD + i];
  }
  const int r0 = blockIdx.x * 32;
  for (int idx = threadIdx.x; idx < 32*CD/4; idx += 192)
    reinterpret_cast<float4*>(al)[idx] =
        reinterpret_cast<const float4*>(h0 + (size_t)r0*CD)[idx];
  __syncthreads();
  const int c = threadIdx.x;
  const int dir = c >= GD;
  const int g = c - dir*GD;
  const float bias = dir ? (bib[g]+bhb[g]) : (bif[g]+bhf[g]);
  const float* wrow = wl + c*53;
  float acc[32];
#pragma unroll
  for (int r=0;r<32;r++) acc[r]=bias;
#pragma unroll 1
  for (int i0=0; i0<CD; i0+=4) {
    float w0=wrow[i0], w1=wrow[i0+1], w2=wrow[i0+2], w3=wrow[i0+3];
#pragma unroll
    for (int r=0;r<32;r++) {
      float4 a4 = *reinterpret_cast<const float4*>(&al[r*CD + i0]);  // broadcast
      acc[r] += a4.x*w0 + a4.y*w1 + a4.z*w2 + a4.w*w3;
    }
  }
  float* op = xg + (size_t)dir*PD*TD*GD + (size_t)r0*GD + g;
#pragma unroll
  for (int r=0;r<32;r++) op[(size_t)r*GD] = acc[r];
}

// ============ bidirectional LSTM (unchanged from r3) ============
__global__ __launch_bounds__(64) void lstm_kernel(
    const float* __restrict__ xg,
    const float* __restrict__ whf, const float* __restrict__ whb,
    float* __restrict__ out, const int mode) {
  const int p = blockIdx.x >> 1;
  const int dir = blockIdx.x & 1;
  const int l = threadIdx.x;
  const float* wh = dir ? whb : whf;
  const int gA = l;
  const int gB = 64 + (l & 31);
  float wA[HID], wB[HID];
#pragma unroll
  for (int j=0;j<HID;j+=4) {
    float4 a4 = *reinterpret_cast<const float4*>(wh + gA*HID + j);
    wA[j]=a4.x; wA[j+1]=a4.y; wA[j+2]=a4.z; wA[j+3]=a4.w;
    float4 b4 = *reinterpret_cast<const float4*>(wh + gB*HID + j);
    wB[j]=b4.x; wB[j+1]=b4.y; wB[j+2]=b4.z; wB[j+3]=b4.w;
  }
  const bool tA = (gA >= 48);
  const bool tB = ((l & 31) < 8);
  const float saA = tA?2.f:1.f, ssA = tA?2.f:1.f, sbA = tA?-1.f:0.f;
  const float saB = tB?2.f:1.f, ssB = tB?2.f:1.f, sbB = tB?-1.f:0.f;
  float h[HID];
#pragma unroll
  for (int j=0;j<HID;j++) h[j]=0.f;
  float c = 0.f;
  const float* xp = xg + ((size_t)dir*PD + p)*TD*GD;
  int t = dir ? TD-1 : 0;
  const int dt = dir ? -1 : 1;
  float xa = xp[t*GD + gA];
  float xb = xp[t*GD + gB];
  for (int s=0; s<TD; ++s) {
    const int tn = t + dt;
    float na = 0.f, nb = 0.f;
    if (s+1 < TD) { na = xp[tn*GD + gA]; nb = xp[tn*GD + gB]; }
    float accA = xa, accB = xb;
#pragma unroll
    for (int j=0;j<HID;j++) { accA += wA[j]*h[j]; accB += wB[j]*h[j]; }
    float vA = actg(saA, ssA, sbA, accA);
    float vB = actg(saB, ssB, sbB, accB);
    float f  = __shfl(vA, (24 + l) & 63);
    float g1 = __shfl(vA, (48 + l) & 63);
    float g2 = __shfl(vB, (l - 16) & 63);
    float o  = __shfl(vB, (8 + l) & 63);
    float gg = (l < 16) ? g1 : g2;
    c = f*c + vA*gg;
    float th = 2.f*__builtin_amdgcn_rcpf(1.f + __expf(-2.f*c)) - 1.f;
    float hn = o * th;
    if (l < HID) {
      if (mode==0) out[((size_t)p*TD + t)*CD + dir*HID + l] = hn;
      else         out[((size_t)t*PD + p)*CD + dir*HID + l] = hn;
    }
#pragma unroll
    for (int j=0;j<HID;j++)
      h[j] = __int_as_float(__builtin_amdgcn_readlane(__float_as_int(hn), j));
    xa = na; xb = nb; t = tn;
  }
}

// ============ qkv projection — xg0-style ============
__global__ __launch_bounds__(192) void qkv_kernel(
    const float* __restrict__ y, const float* __restrict__ wq,
    const float* __restrict__ bq,
    float* __restrict__ Qb, float* __restrict__ Kb, float* __restrict__ Vb) {
  __shared__ float wl[144*53];       // 30.5 KB, stride 53
  __shared__ float al[32*CD];        // 6 KB
  for (int idx = threadIdx.x; idx < 144*CD; idx += 192) {
    int cc = idx / CD, i = idx - cc*CD;
    wl[cc*53 + i] = wq[idx];
  }
  const int r0 = blockIdx.x * 32;
  for (int idx = threadIdx.x; idx < 32*CD/4; idx += 192)
    reinterpret_cast<float4*>(al)[idx] =
        reinterpret_cast<const float4*>(y + (size_t)r0*CD)[idx];
  __syncthreads();
  const int c = threadIdx.x;
  if (c >= 144) return;
  const float bias = bq[c];
  const float* wrow = wl + c*53;
  float acc[32];
#pragma unroll
  for (int r=0;r<32;r++) acc[r]=bias;
#pragma unroll 1
  for (int i0=0; i0<CD; i0+=4) {
    float w0=wrow[i0], w1=wrow[i0+1], w2=wrow[i0+2], w3=wrow[i0+3];
#pragma unroll
    for (int r=0;r<32;r++) {
      float4 a4 = *reinterpret_cast<const float4*>(&al[r*CD + i0]);  // broadcast
      acc[r] += a4.x*w0 + a4.y*w1 + a4.z*w2 + a4.w*w3;
    }
  }
  float* dst; int col; float sc = 1.f;
  if (c < CD)        { dst = Qb; col = c;      sc = 0.28867513459481287f; }
  else if (c < 2*CD) { dst = Kb; col = c-CD; }
  else               { dst = Vb; col = c-2*CD; }
#pragma unroll
  for (int r=0;r<32;r++) dst[(size_t)(r0+r)*CD + col] = acc[r]*sc;
}

// ============ NATTEN 2D (unchanged) ============
__global__ __launch_bounds__(256) void natten_kernel(
    const float* __restrict__ Qb, const float* __restrict__ Kb,
    const float* __restrict__ Vb, const float* __restrict__ rpb,
    float* __restrict__ out) {
  __shared__ float kl[NH*400*HDIM];
  __shared__ float vl[NH*400*HDIM];
  const int tb = blockIdx.x & 15;
  const int wb = blockIdx.x >> 4;
  const int t0 = tb*8, w0 = wb*8;
  const int ht0 = imin(imax(t0-6,0), TD-KW);
  const int hw0 = imin(imax(w0-6,0), PD-KW);
  for (int idx = threadIdx.x; idx < 400*HDIM; idx += 256) {
    int pos = idx / HDIM;
    int c4  = idx - pos*HDIM;
    int lw = pos / 20, lt = pos - lw*20;
    int gt = imin(ht0+lt, TD-1), gw = imin(hw0+lw, PD-1);
    int h = c4 / 3, j = c4 - h*3;
    size_t ga = ((size_t)gt*PD + gw)*CD + c4*4;
    *reinterpret_cast<float4*>(&kl[((size_t)h*400+pos)*HDIM + j*4]) =
        *reinterpret_cast<const float4*>(Kb + ga);
    *reinterpret_cast<float4*>(&vl[((size_t)h*400+pos)*HDIM + j*4]) =
        *reinterpret_cast<const float4*>(Vb + ga);
  }
  __syncthreads();
  const int head = threadIdx.x >> 6;
  const int pix  = threadIdx.x & 63;
  const int pt = pix >> 3, pw = pix & 7;
  const int t = t0+pt, w = w0+pw;
  const int ts = imin(imax(t-6,0), TD-KW);
  const int wsb = imin(imax(w-6,0), PD-KW);
  const int lt0 = ts - ht0, lw0 = wsb - hw0;
  const float* qp = Qb + ((size_t)t*PD + w)*CD + head*HDIM;
  float4 q0 = *reinterpret_cast<const float4*>(qp);
  float4 q1 = *reinterpret_cast<const float4*>(qp+4);
  float4 q2 = *reinterpret_cast<const float4*>(qp+8);
  const float* kb = kl + (size_t)head*4800;
  const float* vb = vl + (size_t)head*4800;
  const float* bb = rpb + head*625 + (ts-t+12)*25 + (wsb-w+12);
  float sum=0.f;
  float o0x=0,o0y=0,o0z=0,o0w=0, o1x=0,o1y=0,o1z=0,o1w=0, o2x=0,o2y=0,o2z=0,o2w=0;
  for (int pp=0; pp<KW; ++pp) {
    const int ltp = lt0+pp;
    const float* br = bb + pp*25;
    for (int qq=0; qq<KW; ++qq) {
      const int pos = (lw0+qq)*20 + ltp;
      const float* kr = kb + pos*HDIM;
      float4 k0=*reinterpret_cast<const float4*>(kr);
      float4 k1=*reinterpret_cast<const float4*>(kr+4);
      float4 k2=*reinterpret_cast<const float4*>(kr+8);
      float lg = br[qq];
      lg += q0.x*k0.x + q0.y*k0.y + q0.z*k0.z + q0.w*k0.w;
      lg += q1.x*k1.x + q1.y*k1.y + q1.z*k1.z + q1.w*k1.w;
      lg += q2.x*k2.x + q2.y*k2.y + q2.z*k2.z + q2.w*k2.w;
      float e = __expf(lg);
      sum += e;
      const float* vr = vb + pos*HDIM;
      float4 v0=*reinterpret_cast<const float4*>(vr);
      float4 v1=*reinterpret_cast<const float4*>(vr+4);
      float4 v2=*reinterpret_cast<const float4*>(vr+8);
      o0x += e*v0.x; o0y += e*v0.y; o0z += e*v0.z; o0w += e*v0.w;
      o1x += e*v1.x; o1y += e*v1.y; o1z += e*v1.z; o1w += e*v1.w;
      o2x += e*v2.x; o2y += e*v2.y; o2z += e*v2.z; o2w += e*v2.w;
    }
  }
  float inv = 1.f/sum;
  float* op = out + ((size_t)t*PD + w)*CD + head*HDIM;
  float4 r0v = {o0x*inv,o0y*inv,o0z*inv,o0w*inv};
  float4 r1v = {o1x*inv,o1y*inv,o1z*inv,o1w*inv};
  float4 r2v = {o2x*inv,o2y*inv,o2z*inv,o2w*inv};
  *reinterpret_cast<float4*>(op)   = r0v;
  *reinterpret_cast<float4*>(op+4) = r1v;
  *reinterpret_cast<float4*>(op+8) = r2v;
}

// ============ output projection — xg0-style ============
__global__ __launch_bounds__(256) void proj_kernel(
    const float* __restrict__ ain, const float* __restrict__ wp,
    const float* __restrict__ bp, float* __restrict__ out) {
  __shared__ float wl[48*53];        // 10.2 KB
  __shared__ float al[32*CD];        // 6 KB
  for (int idx = threadIdx.x; idx < CD*CD; idx += 256) {
    int cc = idx / CD, i = idx - cc*CD;
    wl[cc*53 + i] = wp[idx];
  }
  const int r0 = blockIdx.x * 32;
  for (int idx = threadIdx.x; idx < 32*CD/4; idx += 256)
    reinterpret_cast<float4*>(al)[idx] =
        reinterpret_cast<const float4*>(ain + (size_t)r0*CD)[idx];
  __syncthreads();
  const int c  = threadIdx.x & 63;
  const int rg = threadIdx.x >> 6;   // 0..3 -> rows rg*8..rg*8+7
  if (c >= CD) return;
  const float bias = bp[c];
  const float* wrow = wl + c*53;
  float acc[8];
#pragma unroll
  for (int r=0;r<8;r++) acc[r]=bias;
#pragma unroll 1
  for (int i0=0; i0<CD; i0+=4) {
    float w0=wrow[i0], w1=wrow[i0+1], w2=wrow[i0+2], w3=wrow[i0+3];
#pragma unroll
    for (int r=0;r<8;r++) {
      float4 a4 = *reinterpret_cast<const float4*>(&al[(rg*8+r)*CD + i0]);
      acc[r] += a4.x*w0 + a4.y*w1 + a4.z*w2 + a4.w*w3;
    }
  }
#pragma unroll
  for (int r=0;r<8;r++) out[(size_t)(r0+rg*8+r)*CD + c] = acc[r];
}

extern "C" void kernel_launch(void* const* d_in, const int* in_sizes, int n_in,
                              void* d_out, int out_size, void* d_ws, size_t ws_size,
                              hipStream_t stream) {
  (void)in_sizes; (void)n_in; (void)out_size; (void)ws_size;
  const float* x        = (const float*)d_in[0];
  const float* w_ih_l0  = (const float*)d_in[1];
  const float* w_hh_l0  = (const float*)d_in[2];
  const float* b_ih_l0  = (const float*)d_in[3];
  const float* b_hh_l0  = (const float*)d_in[4];
  const float* w_ih_l0r = (const float*)d_in[5];
  const float* w_hh_l0r = (const float*)d_in[6];
  const float* b_ih_l0r = (const float*)d_in[7];
  const float* b_hh_l0r = (const float*)d_in[8];
  const float* w_ih_l1  = (const float*)d_in[9];
  const float* w_hh_l1  = (const float*)d_in[10];
  const float* b_ih_l1  = (const float*)d_in[11];
  const float* b_hh_l1  = (const float*)d_in[12];
  const float* w_ih_l1r = (const float*)d_in[13];
  const float* w_hh_l1r = (const float*)d_in[14];
  const float* b_ih_l1r = (const float*)d_in[15];
  const float* b_hh_l1r = (const float*)d_in[16];
  const float* w_qkv    = (const float*)d_in[17];
  const float* b_qkv    = (const float*)d_in[18];
  const float* rpb      = (const float*)d_in[19];
  const float* w_proj   = (const float*)d_in[20];
  const float* b_proj   = (const float*)d_in[21];
  float* out = (float*)d_out;

  float* ws = (float*)d_ws;
  const size_t NPIX = (size_t)TD*PD;
  float* XG = ws;
  float* H0 = XG + (size_t)2*PD*TD*GD;
  float* Y  = H0 + NPIX*CD;
  float* Qb = Y  + NPIX*CD;
  float* Kb = Qb + NPIX*CD;
  float* Vb = Kb + NPIX*CD;
  float* AO = Vb + NPIX*CD;

  xg0_kernel<<<dim3(352,2),128,0,stream>>>(x, w_ih_l0, w_ih_l0r, b_ih_l0, b_hh_l0, b_ih_l0r, b_hh_l0r, XG);
  lstm_kernel<<<2*PD,64,0,stream>>>(XG, w_hh_l0, w_hh_l0r, H0, 0);
  xg1_kernel<<<352,192,0,stream>>>(H0, w_ih_l1, w_ih_l1r, b_ih_l1, b_hh_l1, b_ih_l1r, b_hh_l1r, XG);
  lstm_kernel<<<2*PD,64,0,stream>>>(XG, w_hh_l1, w_hh_l1r, Y, 1);

  for (int l=0; l<2; ++l) {
    qkv_kernel<<<352,192,0,stream>>>(Y, w_qkv, b_qkv, Qb, Kb, Vb);
    natten_kernel<<<176,256,0,stream>>>(Qb, Kb, Vb, rpb, AO);
    proj_kernel<<<352,256,0,stream>>>(AO, w_proj, b_proj, (l==1)? out : Y);
  }
}